// Round 4
// baseline (94.638 us; speedup 1.0000x reference)
//
#include <hip/hip_runtime.h>
#include <hip/hip_cooperative_groups.h>
#include <math.h>

namespace cg = cooperative_groups;

#define NN 512
#define D  256   // EMB_DIM == HID

// Single cooperative kernel: 256 blocks x 512 threads, 1+ block/CU, all resident.
// Phase 1 (GEMM):  block b<128 -> x rows 4(b&127)..+3, writes TRANSPOSED hxbT[k][j]
//                  block b>=128 -> y rows, writes hy row-major.
// grid.sync()
// Phase 2 (pair):  block b owns i = {2b, 2b+1}; hy rows + W2 staged in LDS;
//                  thread: jg=t&127 owns j=4jg..4jg+3 (coalesced float4 from hxbT),
//                  ks=t>>7 owns a 64-wide k slice; partials combined in LDS.
//                  exp(softplus(z)) == 1 + exp(z) -> lse_i = log(512 + sum_j exp(z_ij)).
// grid.sync()
// Finalize: block 0 reduces 256 partials in fixed order -> deterministic scalar.
__global__ __launch_bounds__(512) void fused(
    const float* __restrict__ x, const float* __restrict__ y,
    const float* __restrict__ W1, const float* __restrict__ b1,
    const float* __restrict__ W2, const float* __restrict__ b2p,
    float* __restrict__ hxbT, float* __restrict__ hy,
    float* __restrict__ partials, float* __restrict__ out)
{
    cg::grid_group grid = cg::this_grid();
    int b = blockIdx.x;
    int tid = threadIdx.x;

    // ---------------- Phase 1: GEMM ----------------
    {
        bool isx = (b < 128);
        int r0 = (b & 127) * 4 + (tid >> 8) * 2;   // 2 rows per half-block
        int k  = tid & 255;                        // output column
        const float* src = isx ? x : y;
        const float* Wb  = W1 + (isx ? 0 : D * D);

        float bias = isx ? b1[k] : 0.0f;
        float a0 = bias, a1 = bias;

        const float4* s0 = (const float4*)(src + (r0 + 0) * D);
        const float4* s1 = (const float4*)(src + (r0 + 1) * D);

#pragma unroll 4
        for (int m4 = 0; m4 < D / 4; ++m4) {
            float4 v0 = s0[m4], v1 = s1[m4];          // wave-uniform rows
            const float* Wc = Wb + (m4 * 4) * D + k;  // coalesced
            float w0 = Wc[0], w1 = Wc[D], w2 = Wc[2 * D], w3 = Wc[3 * D];
            a0 = fmaf(v0.x, w0, a0); a0 = fmaf(v0.y, w1, a0);
            a0 = fmaf(v0.z, w2, a0); a0 = fmaf(v0.w, w3, a0);
            a1 = fmaf(v1.x, w0, a1); a1 = fmaf(v1.y, w1, a1);
            a1 = fmaf(v1.z, w2, a1); a1 = fmaf(v1.w, w3, a1);
        }

        if (isx) {
            *(float2*)(hxbT + k * NN + r0) = make_float2(a0, a1); // free transpose
        } else {
            hy[(r0 + 0) * D + k] = a0;
            hy[(r0 + 1) * D + k] = a1;
        }
    }

    grid.sync();   // all hxbT / hy visible device-wide

    // ---------------- Phase 2: pairwise z + lse ----------------
    __shared__ float hyS[2][D];
    __shared__ float w2S[D];
    __shared__ float zS[4][2][NN];   // 16 KB: [ks][i][j]
    __shared__ float ws0[8], ws1[8], diagS[2];

    int i0 = b * 2;
    if (tid < 256) {
        hyS[0][tid] = hy[(i0 + 0) * D + tid];
        w2S[tid]    = W2[tid];
    } else {
        int u = tid - 256;
        hyS[1][u] = hy[(i0 + 1) * D + u];
    }
    __syncthreads();

    int jg = tid & 127;      // j-group base 4*jg
    int ks = tid >> 7;       // k-slice 0..3 (wave-uniform)

    float p00 = 0.f, p01 = 0.f, p02 = 0.f, p03 = 0.f;
    float p10 = 0.f, p11 = 0.f, p12 = 0.f, p13 = 0.f;

    const float4* hT   = (const float4*)hxbT;     // rows of 128 float4 over j
    const float4* hy0f = (const float4*)hyS[0];
    const float4* hy1f = (const float4*)hyS[1];
    const float4* w2f  = (const float4*)w2S;
    int g0 = ks * 16;

#pragma unroll 2
    for (int g = 0; g < 16; ++g) {
        int k4 = g0 + g;                          // float4 index over k
        float4 a4 = hy0f[k4];                     // ds_read_b128 broadcast
        float4 c4 = hy1f[k4];
        float4 w4 = w2f[k4];
        float4 h0 = hT[(k4 * 4 + 0) * (NN / 4) + jg];   // coalesced 16B/lane
        float4 h1 = hT[(k4 * 4 + 1) * (NN / 4) + jg];
        float4 h2 = hT[(k4 * 4 + 2) * (NN / 4) + jg];
        float4 h3 = hT[(k4 * 4 + 3) * (NN / 4) + jg];

        // k = 4k4+0 (h0, .x) ... k = 4k4+3 (h3, .w); same k-order as before
        p00 = fmaf(fmaxf(h0.x + a4.x, 0.f), w4.x, p00);
        p01 = fmaf(fmaxf(h0.y + a4.x, 0.f), w4.x, p01);
        p02 = fmaf(fmaxf(h0.z + a4.x, 0.f), w4.x, p02);
        p03 = fmaf(fmaxf(h0.w + a4.x, 0.f), w4.x, p03);
        p10 = fmaf(fmaxf(h0.x + c4.x, 0.f), w4.x, p10);
        p11 = fmaf(fmaxf(h0.y + c4.x, 0.f), w4.x, p11);
        p12 = fmaf(fmaxf(h0.z + c4.x, 0.f), w4.x, p12);
        p13 = fmaf(fmaxf(h0.w + c4.x, 0.f), w4.x, p13);

        p00 = fmaf(fmaxf(h1.x + a4.y, 0.f), w4.y, p00);
        p01 = fmaf(fmaxf(h1.y + a4.y, 0.f), w4.y, p01);
        p02 = fmaf(fmaxf(h1.z + a4.y, 0.f), w4.y, p02);
        p03 = fmaf(fmaxf(h1.w + a4.y, 0.f), w4.y, p03);
        p10 = fmaf(fmaxf(h1.x + c4.y, 0.f), w4.y, p10);
        p11 = fmaf(fmaxf(h1.y + c4.y, 0.f), w4.y, p11);
        p12 = fmaf(fmaxf(h1.z + c4.y, 0.f), w4.y, p12);
        p13 = fmaf(fmaxf(h1.w + c4.y, 0.f), w4.y, p13);

        p00 = fmaf(fmaxf(h2.x + a4.z, 0.f), w4.z, p00);
        p01 = fmaf(fmaxf(h2.y + a4.z, 0.f), w4.z, p01);
        p02 = fmaf(fmaxf(h2.z + a4.z, 0.f), w4.z, p02);
        p03 = fmaf(fmaxf(h2.w + a4.z, 0.f), w4.z, p03);
        p10 = fmaf(fmaxf(h2.x + c4.z, 0.f), w4.z, p10);
        p11 = fmaf(fmaxf(h2.y + c4.z, 0.f), w4.z, p11);
        p12 = fmaf(fmaxf(h2.z + c4.z, 0.f), w4.z, p12);
        p13 = fmaf(fmaxf(h2.w + c4.z, 0.f), w4.z, p13);

        p00 = fmaf(fmaxf(h3.x + a4.w, 0.f), w4.w, p00);
        p01 = fmaf(fmaxf(h3.y + a4.w, 0.f), w4.w, p01);
        p02 = fmaf(fmaxf(h3.z + a4.w, 0.f), w4.w, p02);
        p03 = fmaf(fmaxf(h3.w + a4.w, 0.f), w4.w, p03);
        p10 = fmaf(fmaxf(h3.x + c4.w, 0.f), w4.w, p10);
        p11 = fmaf(fmaxf(h3.y + c4.w, 0.f), w4.w, p11);
        p12 = fmaf(fmaxf(h3.z + c4.w, 0.f), w4.w, p12);
        p13 = fmaf(fmaxf(h3.w + c4.w, 0.f), w4.w, p13);
    }

    *(float4*)&zS[ks][0][4 * jg] = make_float4(p00, p01, p02, p03);
    *(float4*)&zS[ks][1][4 * jg] = make_float4(p10, p11, p12, p13);
    __syncthreads();

    // thread t == j
    float b2 = b2p[0];
    float z0 = zS[0][0][tid] + zS[1][0][tid] + zS[2][0][tid] + zS[3][0][tid] + b2;
    float z1 = zS[0][1][tid] + zS[1][1][tid] + zS[2][1][tid] + zS[3][1][tid] + b2;
    float e0 = expf(z0), e1 = expf(z1);   // exp(softplus(z)) = 1 + e^z ("+1" later)

    int lane = tid & 63, wid = tid >> 6;
    if (tid == i0)     diagS[0] = fmaxf(z0, 0.f) + log1pf(expf(-fabsf(z0)));
    if (tid == i0 + 1) diagS[1] = fmaxf(z1, 0.f) + log1pf(expf(-fabsf(z1)));

    float s0 = e0, s1 = e1;
#pragma unroll
    for (int off = 32; off >= 1; off >>= 1) {
        s0 += __shfl_xor(s0, off);
        s1 += __shfl_xor(s1, off);
    }
    if (lane == 0) { ws0[wid] = s0; ws1[wid] = s1; }
    __syncthreads();

    if (tid == 0) {
        float tot0 = 512.0f, tot1 = 512.0f;   // the "+1" from each of 512 j's
#pragma unroll
        for (int w = 0; w < 8; ++w) { tot0 += ws0[w]; tot1 += ws1[w]; }
        float lse0 = logf(tot0), lse1 = logf(tot1);
        float part = (lse0 - diagS[0] + lse1 - diagS[1]) * (1.0f / 512.0f);
        if (b == 0) part -= logf(512.0f);
        partials[b] = part;                   // ordered by grid.sync below
    }

    grid.sync();

    // ---------------- Finalize: block 0, fixed order ----------------
    if (b == 0 && tid < 64) {
        float s = 0.0f;
#pragma unroll
        for (int q = 0; q < 4; ++q)
            s += partials[tid + 64 * q];
#pragma unroll
        for (int off = 32; off >= 1; off >>= 1) s += __shfl_xor(s, off);
        if (tid == 0) out[0] = s;   // = mean(lse) - log N - mean(T0)
    }
}

extern "C" void kernel_launch(void* const* d_in, const int* in_sizes, int n_in,
                              void* d_out, int out_size, void* d_ws, size_t ws_size,
                              hipStream_t stream)
{
    const float* x  = (const float*)d_in[0];
    const float* y  = (const float*)d_in[1];
    const float* W1 = (const float*)d_in[2];
    const float* b1 = (const float*)d_in[3];
    const float* W2 = (const float*)d_in[4];
    const float* b2 = (const float*)d_in[5];
    float* out = (float*)d_out;

    float* ws   = (float*)d_ws;
    float* hxbT = ws;                        // 256 k x 512 j
    float* hy   = ws + NN * D;               // 512 x 256
    float* partials = ws + 2 * NN * D;       // 256

    void* args[] = {
        (void*)&x, (void*)&y, (void*)&W1, (void*)&b1, (void*)&W2, (void*)&b2,
        (void*)&hxbT, (void*)&hy, (void*)&partials, (void*)&out
    };
    hipLaunchCooperativeKernel((const void*)fused, dim3(256), dim3(512),
                               args, 0, stream);
}